// Round 10
// baseline (763.691 us; speedup 1.0000x reference)
//
#include <hip/hip_runtime.h>

#define NUSR 60000
#define NITM 40000
#define NN   100000
#define EE   2000000
#define HD   128

#define BW   512                 // bucket width in nodes (CSR build)
#define NB   196                 // ceil(NN / BW)
#define EPB  8192                // edges per block in binning kernels
#define NPB  128                 // nodes per agg-slice block

using bf16x8   = __attribute__((ext_vector_type(8))) short;
using f32x4    = __attribute__((ext_vector_type(4))) float;
using ushort4t = __attribute__((ext_vector_type(4))) unsigned short;
using ushort2t = __attribute__((ext_vector_type(2))) unsigned short;
using uint4t   = __attribute__((ext_vector_type(4))) unsigned int;

__device__ __forceinline__ unsigned short f2bf(float f) {
    unsigned int u = __float_as_uint(f);
    u += 0x7FFFu + ((u >> 16) & 1u);           // round-to-nearest-even
    return (unsigned short)(u >> 16);
}
__device__ __forceinline__ float bf2f(unsigned short s) {
    return __uint_as_float(((unsigned int)s) << 16);
}
// order-preserving bf16 <-> u16 key (unsigned compare order == float order)
__device__ __forceinline__ unsigned short keyof(unsigned short b) {
    return (b & 0x8000u) ? (unsigned short)~b : (unsigned short)(b | 0x8000u);
}
// packed inverse key map on a u32 (2 keys)
__device__ __forceinline__ unsigned unkey32(unsigned k) {
    unsigned negsel = (~k & 0x80008000u) >> 15;
    return k ^ (0x80008000u | (negsel * 0x7FFFu));
}
__device__ __forceinline__ int swz(int row, int col) {
    return row * HD + (col ^ ((row & 7) << 3));
}

// ---------------- CSR build via 2-level bucket binning ----------------
__global__ __launch_bounds__(256) void bhist_k(const int* __restrict__ dst,
                                               int* __restrict__ bcnt) {
    __shared__ int h[NB];
    int t = threadIdx.x;
    if (t < NB) h[t] = 0;
    __syncthreads();
    int e0 = blockIdx.x * EPB;
    #pragma unroll 4
    for (int i = t; i < EPB; i += 256) {
        int e = e0 + i;
        if (e < EE) atomicAdd(&h[dst[e] >> 9], 1);
    }
    __syncthreads();
    if (t < NB && h[t]) atomicAdd(&bcnt[t], h[t]);
}

__global__ void bscan_k(const int* __restrict__ bcnt, int* __restrict__ bbase,
                        int* __restrict__ bcur, int* __restrict__ off) {
    __shared__ int s[256];
    int t = threadIdx.x;
    int v = (t < NB) ? bcnt[t] : 0;
    s[t] = v;
    __syncthreads();
    for (int d = 1; d < 256; d <<= 1) {
        int a = (t >= d) ? s[t - d] : 0;
        __syncthreads();
        s[t] += a;
        __syncthreads();
    }
    if (t < NB) { bbase[t] = s[t] - v; bcur[t] = s[t] - v; }
    if (t == NB - 1) { bbase[NB] = s[t]; off[NN] = EE; }
}

__global__ __launch_bounds__(256) void bscatter_k(const int* __restrict__ src,
                                                  const int* __restrict__ dst,
                                                  int* __restrict__ bcur,
                                                  unsigned int* __restrict__ bedge) {
    __shared__ int h[NB], base[NB];
    int t = threadIdx.x;
    if (t < NB) h[t] = 0;
    __syncthreads();
    int e0 = blockIdx.x * EPB;
    #pragma unroll 4
    for (int i = t; i < EPB; i += 256) {
        int e = e0 + i;
        if (e < EE) atomicAdd(&h[dst[e] >> 9], 1);
    }
    __syncthreads();
    if (t < NB) {
        int c = h[t];
        base[t] = c ? atomicAdd(&bcur[t], c) : 0;
        h[t] = 0;
    }
    __syncthreads();
    #pragma unroll 4
    for (int i = t; i < EPB; i += 256) {
        int e = e0 + i;
        if (e < EE) {
            int d = dst[e];
            int b = d >> 9;
            int p = base[b] + atomicAdd(&h[b], 1);
            bedge[p] = ((unsigned)(d - (b << 9)) << 17) | (unsigned)src[e];
        }
    }
}

__global__ __launch_bounds__(512) void bcsr_k(const unsigned int* __restrict__ bedge,
                                              const int* __restrict__ bbase,
                                              int* __restrict__ off,
                                              int* __restrict__ csr) {
    __shared__ int cnt[BW], cur[BW], sc[BW];
    int b = blockIdx.x, t = threadIdx.x;
    int n0 = b * BW;
    int nloc = min(BW, NN - n0);
    cnt[t] = 0;
    __syncthreads();
    int e0 = bbase[b], e1 = bbase[b + 1];
    for (int e = e0 + t; e < e1; e += 512)
        atomicAdd(&cnt[bedge[e] >> 17], 1);
    __syncthreads();
    int v = cnt[t];
    sc[t] = v;
    __syncthreads();
    for (int d = 1; d < BW; d <<= 1) {
        int a = (t >= d) ? sc[t - d] : 0;
        __syncthreads();
        sc[t] += a;
        __syncthreads();
    }
    int excl = sc[t] - v;
    if (t < nloc) { off[n0 + t] = e0 + excl; cur[t] = e0 + excl; }
    __syncthreads();
    for (int e = e0 + t; e < e1; e += 512) {
        unsigned ed = bedge[e];
        int p = atomicAdd(&cur[ed >> 17], 1);
        csr[p] = (int)(ed & 0x1FFFFu);
    }
}

// ---- fp32 -> bf16 row-major weights; wr0/wr1 (m=3,5) get +I (residual fold) --
__global__ void cvt6i_k(const float* __restrict__ a0, const float* __restrict__ a1,
                        const float* __restrict__ a2, const float* __restrict__ a3,
                        const float* __restrict__ a4, const float* __restrict__ a5,
                        unsigned short* __restrict__ out) {
    int i = blockIdx.x * 256 + threadIdx.x;
    int m = i >> 14, idx = i & 16383;
    const float* s;
    switch (m) {
        case 0: s = a0; break; case 1: s = a1; break; case 2: s = a2; break;
        case 3: s = a3; break; case 4: s = a4; break; default: s = a5; break;
    }
    float v = s[idx];
    if ((m == 3 || m == 5) && (idx >> 7) == (idx & 127)) v += 1.0f;
    out[i] = f2bf(v);
}

// -------- proj: hkey[row] = key(bf16( x[row] @ w.T + b )), MFMA --------
__global__ __launch_bounds__(256) void proj_mfma_k(
    const float* __restrict__ x, const unsigned short* __restrict__ wb,
    const float* __restrict__ bias, unsigned short* __restrict__ hkey,
    int row_base, int nrows) {
    __shared__ unsigned short lw[HD * HD];       // weights, then reused as key stage
    int tid = threadIdx.x;
    #pragma unroll
    for (int it = 0; it < 16; ++it) {
        int flat = (it * 256 + tid) * 4;
        int row = flat >> 7, col = flat & 127;
        *(ushort4t*)&lw[swz(row, col)] = *(const ushort4t*)(wb + flat);
    }
    __syncthreads();
    int lane = tid & 63, w = tid >> 6;
    int l15 = lane & 15, l4 = lane >> 4;
    int m0 = blockIdx.x * 128 + w * 32;
    f32x4 acc[2][8] = {};
    #pragma unroll
    for (int kb = 0; kb < 4; ++kb) {
        bf16x8 a[2];
        #pragma unroll
        for (int rt = 0; rt < 2; ++rt) {
            int r = m0 + rt * 16 + l15;
            if (r >= nrows) r = nrows - 1;
            const float* ap = x + (size_t)(row_base + r) * HD + kb * 32 + l4 * 8;
            f32x4 v0 = *(const f32x4*)ap;
            f32x4 v1 = *(const f32x4*)(ap + 4);
            bf16x8 f;
            #pragma unroll
            for (int j = 0; j < 4; ++j) { f[j] = (short)f2bf(v0[j]); f[j + 4] = (short)f2bf(v1[j]); }
            a[rt] = f;
        }
        #pragma unroll
        for (int ct = 0; ct < 8; ++ct) {
            bf16x8 b = *(const bf16x8*)&lw[swz(ct * 16 + l15, kb * 32 + l4 * 8)];
            acc[0][ct] = __builtin_amdgcn_mfma_f32_16x16x32_bf16(a[0], b, acc[0][ct], 0, 0, 0);
            acc[1][ct] = __builtin_amdgcn_mfma_f32_16x16x32_bf16(a[1], b, acc[1][ct], 0, 0, 0);
        }
    }
    __syncthreads();                              // weight reads done
    #pragma unroll
    for (int ct = 0; ct < 8; ++ct) {
        int col = ct * 16 + l15;
        float bv = bias[col];
        #pragma unroll
        for (int rt = 0; rt < 2; ++rt)
            #pragma unroll
            for (int j = 0; j < 4; ++j) {
                int lrow = w * 32 + rt * 16 + l4 * 4 + j;
                lw[lrow * HD + ((col + ((lrow & 15) << 3)) & 127)] =
                    keyof(f2bf(acc[rt][ct][j] + bv));
            }
    }
    __syncthreads();
    int row = tid >> 1, cb = (tid & 1) * 64;
    int r = blockIdx.x * 128 + row;
    if (r < nrows) {
        int sof = (row & 15) << 3;
        #pragma unroll
        for (int gg = 0; gg < 8; ++gg) {
            uint4t v = *(const uint4t*)&lw[row * HD + ((cb + gg * 8 + sof) & 127)];
            *(uint4t*)(hkey + (size_t)(row_base + r) * HD + cb + gg * 8) = v;
        }
    }
}

// -------- XCD-sliced segment max: block b -> slice b&7 (pinned to one XCD
// by round-robin dispatch), nodes [(b>>3)*NPB ...). Slice = 16 features = 32B,
// 3.2 MB/XCD -> L2-resident. Output is SLICE-MAJOR for full-line writes. -----
__global__ __launch_bounds__(256) void agg_slice_k(
    const unsigned* __restrict__ hk32,           // row-major keys: node*64 u32
    const int* __restrict__ off, const int* __restrict__ csr,
    unsigned* __restrict__ aggS32) {             // [slice][node][8 u32] values
    int b = blockIdx.x;
    int slice = b & 7;
    int n0 = (b >> 3) * NPB;
    int n1 = min(n0 + NPB, NN);
    int wv = threadIdx.x >> 6, lane = threadIdx.x & 63;
    int oct = lane >> 3, d = lane & 7;           // 8 octs x 8 dwords
    unsigned sb = slice * 8 + d;
    for (int n = n0 + wv; n < n1; n += 4) {
        int s0 = off[n], s1 = off[n + 1];
        ushort2t m = {0, 0};                     // 0 < key(any finite bf16)
        for (int j = s0 + oct; j < s1; j += 8) { // oct handles every 8th edge
            int r = csr[j];
            unsigned v = hk32[(size_t)r * 64 + sb];
            m = __builtin_elementwise_max(m, *(ushort2t*)&v);
        }
        unsigned a = *(unsigned*)&m;
        #pragma unroll
        for (int x = 8; x < 64; x <<= 1) {
            unsigned o = (unsigned)__shfl_xor((int)a, x, 64);
            ushort2t pa = *(ushort2t*)&a, pb = *(ushort2t*)&o;
            pa = __builtin_elementwise_max(pa, pb);
            a = *(unsigned*)&pa;
        }
        if (oct == 0)
            aggS32[(size_t)slice * NN * 8 + (size_t)n * 8 + d] =
                (s1 > s0) ? unkey32(a) : 0u;
    }
}

// ----- combine: out = bl + agg@wl.T + h@(wr+I).T (relu?) -----
// 512 threads / 8 waves / 256 rows; LDS-staged weights; two-phase fp32 epilogue.
__global__ __launch_bounds__(512) void combine_mfma_k(
    const unsigned short* __restrict__ hkey, const unsigned short* __restrict__ aggS,
    const unsigned short* __restrict__ wlb, const float* __restrict__ bl,
    const unsigned short* __restrict__ wrb,
    unsigned short* __restrict__ hkey_out, float* __restrict__ fout, int relu) {
    __shared__ unsigned short lw[2][HD * HD];    // 64 KB weights; reused as fp32 C
    int tid = threadIdx.x;
    #pragma unroll
    for (int it = 0; it < 8; ++it) {
        int flat = (it * 512 + tid) * 4;
        int row = flat >> 7, col = flat & 127;
        *(ushort4t*)&lw[0][swz(row, col)] = *(const ushort4t*)(wlb + flat);
        *(ushort4t*)&lw[1][swz(row, col)] = *(const ushort4t*)(wrb + flat);
    }
    __syncthreads();
    int lane = tid & 63, w = tid >> 6;           // 8 waves
    int l15 = lane & 15, l4 = lane >> 4;
    int m0 = blockIdx.x * 256 + w * 32;
    const uint4t* hk4 = (const uint4t*)hkey;
    f32x4 acc[2][8] = {};
    #pragma unroll
    for (int kb = 0; kb < 4; ++kb) {
        bf16x8 a1[2], a2[2];
        int sl = kb * 2 + (l4 >> 1);             // slice of this k-range
        #pragma unroll
        for (int rt = 0; rt < 2; ++rt) {
            int r = m0 + rt * 16 + l15;
            if (r >= NN) r = NN - 1;
            a1[rt] = *(const bf16x8*)(aggS + ((size_t)sl * NN + r) * 16 + (l4 & 1) * 8);
            uint4t aw = hk4[(size_t)r * 16 + kb * 4 + l4];
            bf16x8 f;
            #pragma unroll
            for (int u = 0; u < 4; ++u) {
                unsigned d = unkey32(aw[u]);
                f[2 * u]     = (short)(d & 0xFFFFu);
                f[2 * u + 1] = (short)(d >> 16);
            }
            a2[rt] = f;
        }
        #pragma unroll
        for (int ct = 0; ct < 8; ++ct) {
            bf16x8 b1 = *(const bf16x8*)&lw[0][swz(ct * 16 + l15, kb * 32 + l4 * 8)];
            bf16x8 b2 = *(const bf16x8*)&lw[1][swz(ct * 16 + l15, kb * 32 + l4 * 8)];
            acc[0][ct] = __builtin_amdgcn_mfma_f32_16x16x32_bf16(a1[0], b1, acc[0][ct], 0, 0, 0);
            acc[0][ct] = __builtin_amdgcn_mfma_f32_16x16x32_bf16(a2[0], b2, acc[0][ct], 0, 0, 0);
            acc[1][ct] = __builtin_amdgcn_mfma_f32_16x16x32_bf16(a1[1], b1, acc[1][ct], 0, 0, 0);
            acc[1][ct] = __builtin_amdgcn_mfma_f32_16x16x32_bf16(a2[1], b2, acc[1][ct], 0, 0, 0);
        }
    }
    __syncthreads();                              // weight reads done
    float* cs = (float*)lw;                       // 128 rows x 128 cols fp32
    for (int p = 0; p < 2; ++p) {
        if ((w >> 2) == p) {
            #pragma unroll
            for (int ct = 0; ct < 8; ++ct)
                #pragma unroll
                for (int rt = 0; rt < 2; ++rt)
                    #pragma unroll
                    for (int j = 0; j < 4; ++j) {
                        int lrow = (w & 3) * 32 + rt * 16 + l4 * 4 + j;
                        int col = ct * 16 + l15;
                        cs[lrow * HD + ((col + lrow * 4) & 127)] = acc[rt][ct][j];
                    }
        }
        __syncthreads();
        int lrow = tid >> 2, cq = (tid & 3) * 32;
        int r = blockIdx.x * 256 + p * 128 + lrow;
        if (r < NN) {
            const float* crow = cs + lrow * HD;
            int rot = lrow * 4;
            #pragma unroll
            for (int gg = 0; gg < 4; ++gg) {
                int c0 = cq + gg * 8;
                f32x4 cv0 = *(const f32x4*)&crow[(c0 + rot) & 127];
                f32x4 cv1 = *(const f32x4*)&crow[(c0 + 4 + rot) & 127];
                f32x4 bv0 = *(const f32x4*)(bl + c0);
                f32x4 bv1 = *(const f32x4*)(bl + c0 + 4);
                float v[8];
                #pragma unroll
                for (int u = 0; u < 4; ++u) { v[u] = cv0[u] + bv0[u]; v[u + 4] = cv1[u] + bv1[u]; }
                if (relu) {
                    #pragma unroll
                    for (int u = 0; u < 8; ++u) v[u] = fmaxf(v[u], 0.0f);
                }
                if (fout) {
                    f32x4 o0 = {v[0], v[1], v[2], v[3]};
                    f32x4 o1 = {v[4], v[5], v[6], v[7]};
                    *(f32x4*)(fout + (size_t)r * HD + c0) = o0;
                    *(f32x4*)(fout + (size_t)r * HD + c0 + 4) = o1;
                } else {
                    uint4t ov;
                    #pragma unroll
                    for (int u = 0; u < 4; ++u)
                        ov[u] = (unsigned)keyof(f2bf(v[2 * u]))
                              | ((unsigned)keyof(f2bf(v[2 * u + 1])) << 16);
                    *(uint4t*)(hkey_out + (size_t)r * HD + c0) = ov;
                }
            }
        }
        __syncthreads();
    }
}

extern "C" void kernel_launch(void* const* d_in, const int* in_sizes, int n_in,
                              void* d_out, int out_size, void* d_ws, size_t ws_size,
                              hipStream_t stream) {
    const float* x      = (const float*)d_in[0];
    const int*   ei     = (const int*)d_in[1];
    const float* w_user = (const float*)d_in[3];
    const float* b_user = (const float*)d_in[4];
    const float* w_item = (const float*)d_in[5];
    const float* b_item = (const float*)d_in[6];
    const float* w_l0   = (const float*)d_in[7];
    const float* b_l0   = (const float*)d_in[8];
    const float* w_r0   = (const float*)d_in[9];
    const float* w_l1   = (const float*)d_in[10];
    const float* b_l1   = (const float*)d_in[11];
    const float* w_r1   = (const float*)d_in[12];

    const int* e_src = ei;
    const int* e_dst = ei + EE;

    char* ws = (char*)d_ws;
    size_t cur_off = 0;
    auto carve = [&](size_t bytes) {
        void* p = ws + cur_off;
        cur_off = (cur_off + bytes + 255) & ~(size_t)255;
        return p;
    };
    unsigned short* hkey0 = (unsigned short*)carve((size_t)NN * HD * 2);  // 25.6 MB
    unsigned short* hkey1 = (unsigned short*)carve((size_t)NN * HD * 2);
    unsigned short* aggS  = (unsigned short*)carve((size_t)NN * HD * 2);  // slice-major
    unsigned short* wb    = (unsigned short*)carve((size_t)6 * HD * HD * 2);
    int*      off   = (int*)carve((size_t)(NN + 1) * 4);
    int*      csr   = (int*)carve((size_t)EE * 4);
    unsigned* bedge = (unsigned*)carve((size_t)EE * 4);
    int*      bcnt  = (int*)carve((NB + 1) * 4);
    int*      bbase = (int*)carve((NB + 1) * 4);
    int*      bcur  = (int*)carve((NB + 1) * 4);
    (void)ws_size;

    // ---- CSR build (bucket binning) ----
    hipMemsetAsync(bcnt, 0, (size_t)NB * 4, stream);
    int nbB = (EE + EPB - 1) / EPB;
    bhist_k<<<nbB, 256, 0, stream>>>(e_dst, bcnt);
    bscan_k<<<1, 256, 0, stream>>>(bcnt, bbase, bcur, off);
    bscatter_k<<<nbB, 256, 0, stream>>>(e_src, e_dst, bcur, bedge);
    bcsr_k<<<NB, 512, 0, stream>>>(bedge, bbase, off, csr);

    // ---- weights -> bf16 row-major (wr0/wr1 get +I) ----
    cvt6i_k<<<(6 * HD * HD) / 256, 256, 0, stream>>>(w_user, w_item, w_l0, w_r0, w_l1, w_r1, wb);

    // ---- input projection (per node type), keys only ----
    proj_mfma_k<<<(NUSR + 127) / 128, 256, 0, stream>>>(x, wb,         b_user, hkey0, 0,    NUSR);
    proj_mfma_k<<<(NITM + 127) / 128, 256, 0, stream>>>(x, wb + 16384, b_item, hkey0, NUSR, NITM);

    int aggGrid = ((NN + NPB - 1) / NPB) * 8;    // 6256 blocks, slice = bid & 7
    // ---- layer 0 ----
    agg_slice_k<<<aggGrid, 256, 0, stream>>>((const unsigned*)hkey0, off, csr, (unsigned*)aggS);
    combine_mfma_k<<<(NN + 255) / 256, 512, 0, stream>>>(
        hkey0, aggS, wb + 2 * 16384, b_l0, wb + 3 * 16384, hkey1, nullptr, 1);

    // ---- layer 1 ----
    agg_slice_k<<<aggGrid, 256, 0, stream>>>((const unsigned*)hkey1, off, csr, (unsigned*)aggS);
    combine_mfma_k<<<(NN + 255) / 256, 512, 0, stream>>>(
        hkey1, aggS, wb + 4 * 16384, b_l1, wb + 5 * 16384, nullptr, (float*)d_out, 0);
}

// Round 11
// 305.399 us; speedup vs baseline: 2.5006x; 2.5006x over previous
//
#include <hip/hip_runtime.h>

#define NUSR 60000
#define NITM 40000
#define NN   100000
#define EE   2000000
#define HD   128

#define BW   512                 // bucket width in nodes (CSR build)
#define NB   196                 // ceil(NN / BW)
#define EPB  8192                // edges per block in binning kernels

using bf16x8   = __attribute__((ext_vector_type(8))) short;
using f32x4    = __attribute__((ext_vector_type(4))) float;
using ushort4t = __attribute__((ext_vector_type(4))) unsigned short;
using ushort2t = __attribute__((ext_vector_type(2))) unsigned short;
using ushort8t = __attribute__((ext_vector_type(8))) unsigned short;
using uint4t   = __attribute__((ext_vector_type(4))) unsigned int;

__device__ __forceinline__ unsigned short f2bf(float f) {
    unsigned int u = __float_as_uint(f);
    u += 0x7FFFu + ((u >> 16) & 1u);           // round-to-nearest-even
    return (unsigned short)(u >> 16);
}
__device__ __forceinline__ float bf2f(unsigned short s) {
    return __uint_as_float(((unsigned int)s) << 16);
}
// order-preserving bf16 <-> u16 key (unsigned compare order == float order)
__device__ __forceinline__ unsigned short keyof(unsigned short b) {
    return (b & 0x8000u) ? (unsigned short)~b : (unsigned short)(b | 0x8000u);
}
// packed inverse key map on a u32 (2 keys)
__device__ __forceinline__ unsigned unkey32(unsigned k) {
    unsigned negsel = (~k & 0x80008000u) >> 15;
    return k ^ (0x80008000u | (negsel * 0x7FFFu));
}
__device__ __forceinline__ int swz(int row, int col) {
    return row * HD + (col ^ ((row & 7) << 3));
}
__device__ __forceinline__ ushort8t pkmax8(ushort8t a, ushort8t b) {
    return __builtin_elementwise_max(a, b);
}

// ---------------- CSR build via 2-level bucket binning ----------------
__global__ __launch_bounds__(256) void bhist_k(const int* __restrict__ dst,
                                               int* __restrict__ bcnt) {
    __shared__ int h[NB];
    int t = threadIdx.x;
    if (t < NB) h[t] = 0;
    __syncthreads();
    int e0 = blockIdx.x * EPB;
    #pragma unroll 4
    for (int i = t; i < EPB; i += 256) {
        int e = e0 + i;
        if (e < EE) atomicAdd(&h[dst[e] >> 9], 1);
    }
    __syncthreads();
    if (t < NB && h[t]) atomicAdd(&bcnt[t], h[t]);
}

__global__ void bscan_k(const int* __restrict__ bcnt, int* __restrict__ bbase,
                        int* __restrict__ bcur, int* __restrict__ off) {
    __shared__ int s[256];
    int t = threadIdx.x;
    int v = (t < NB) ? bcnt[t] : 0;
    s[t] = v;
    __syncthreads();
    for (int d = 1; d < 256; d <<= 1) {
        int a = (t >= d) ? s[t - d] : 0;
        __syncthreads();
        s[t] += a;
        __syncthreads();
    }
    if (t < NB) { bbase[t] = s[t] - v; bcur[t] = s[t] - v; }
    if (t == NB - 1) { bbase[NB] = s[t]; off[NN] = EE; }
}

__global__ __launch_bounds__(256) void bscatter_k(const int* __restrict__ src,
                                                  const int* __restrict__ dst,
                                                  int* __restrict__ bcur,
                                                  unsigned int* __restrict__ bedge) {
    __shared__ int h[NB], base[NB];
    int t = threadIdx.x;
    if (t < NB) h[t] = 0;
    __syncthreads();
    int e0 = blockIdx.x * EPB;
    #pragma unroll 4
    for (int i = t; i < EPB; i += 256) {
        int e = e0 + i;
        if (e < EE) atomicAdd(&h[dst[e] >> 9], 1);
    }
    __syncthreads();
    if (t < NB) {
        int c = h[t];
        base[t] = c ? atomicAdd(&bcur[t], c) : 0;
        h[t] = 0;
    }
    __syncthreads();
    #pragma unroll 4
    for (int i = t; i < EPB; i += 256) {
        int e = e0 + i;
        if (e < EE) {
            int d = dst[e];
            int b = d >> 9;
            int p = base[b] + atomicAdd(&h[b], 1);
            bedge[p] = ((unsigned)(d - (b << 9)) << 17) | (unsigned)src[e];
        }
    }
}

__global__ __launch_bounds__(512) void bcsr_k(const unsigned int* __restrict__ bedge,
                                              const int* __restrict__ bbase,
                                              int* __restrict__ off,
                                              int* __restrict__ csr) {
    __shared__ int cnt[BW], cur[BW], sc[BW];
    int b = blockIdx.x, t = threadIdx.x;
    int n0 = b * BW;
    int nloc = min(BW, NN - n0);
    cnt[t] = 0;
    __syncthreads();
    int e0 = bbase[b], e1 = bbase[b + 1];
    for (int e = e0 + t; e < e1; e += 512)
        atomicAdd(&cnt[bedge[e] >> 17], 1);
    __syncthreads();
    int v = cnt[t];
    sc[t] = v;
    __syncthreads();
    for (int d = 1; d < BW; d <<= 1) {
        int a = (t >= d) ? sc[t - d] : 0;
        __syncthreads();
        sc[t] += a;
        __syncthreads();
    }
    int excl = sc[t] - v;
    if (t < nloc) { off[n0 + t] = e0 + excl; cur[t] = e0 + excl; }
    __syncthreads();
    for (int e = e0 + t; e < e1; e += 512) {
        unsigned ed = bedge[e];
        int p = atomicAdd(&cur[ed >> 17], 1);
        csr[p] = (int)(ed & 0x1FFFFu);
    }
}

// ---- fp32 -> bf16 row-major weights; wr0/wr1 (m=3,5) get +I (residual fold) --
__global__ void cvt6i_k(const float* __restrict__ a0, const float* __restrict__ a1,
                        const float* __restrict__ a2, const float* __restrict__ a3,
                        const float* __restrict__ a4, const float* __restrict__ a5,
                        unsigned short* __restrict__ out) {
    int i = blockIdx.x * 256 + threadIdx.x;
    int m = i >> 14, idx = i & 16383;
    const float* s;
    switch (m) {
        case 0: s = a0; break; case 1: s = a1; break; case 2: s = a2; break;
        case 3: s = a3; break; case 4: s = a4; break; default: s = a5; break;
    }
    float v = s[idx];
    if ((m == 3 || m == 5) && (idx >> 7) == (idx & 127)) v += 1.0f;
    out[i] = f2bf(v);
}

// -------- proj: hkey[row] = key(bf16( x[row] @ w.T + b )), MFMA --------
__global__ __launch_bounds__(256) void proj_mfma_k(
    const float* __restrict__ x, const unsigned short* __restrict__ wb,
    const float* __restrict__ bias, unsigned short* __restrict__ hkey,
    int row_base, int nrows) {
    __shared__ unsigned short lw[HD * HD];       // weights, then reused as key stage
    int tid = threadIdx.x;
    #pragma unroll
    for (int it = 0; it < 16; ++it) {
        int flat = (it * 256 + tid) * 4;
        int row = flat >> 7, col = flat & 127;
        *(ushort4t*)&lw[swz(row, col)] = *(const ushort4t*)(wb + flat);
    }
    __syncthreads();
    int lane = tid & 63, w = tid >> 6;
    int l15 = lane & 15, l4 = lane >> 4;
    int m0 = blockIdx.x * 128 + w * 32;
    f32x4 acc[2][8] = {};
    #pragma unroll
    for (int kb = 0; kb < 4; ++kb) {
        bf16x8 a[2];
        #pragma unroll
        for (int rt = 0; rt < 2; ++rt) {
            int r = m0 + rt * 16 + l15;
            if (r >= nrows) r = nrows - 1;
            const float* ap = x + (size_t)(row_base + r) * HD + kb * 32 + l4 * 8;
            f32x4 v0 = *(const f32x4*)ap;
            f32x4 v1 = *(const f32x4*)(ap + 4);
            bf16x8 f;
            #pragma unroll
            for (int j = 0; j < 4; ++j) { f[j] = (short)f2bf(v0[j]); f[j + 4] = (short)f2bf(v1[j]); }
            a[rt] = f;
        }
        #pragma unroll
        for (int ct = 0; ct < 8; ++ct) {
            bf16x8 b = *(const bf16x8*)&lw[swz(ct * 16 + l15, kb * 32 + l4 * 8)];
            acc[0][ct] = __builtin_amdgcn_mfma_f32_16x16x32_bf16(a[0], b, acc[0][ct], 0, 0, 0);
            acc[1][ct] = __builtin_amdgcn_mfma_f32_16x16x32_bf16(a[1], b, acc[1][ct], 0, 0, 0);
        }
    }
    __syncthreads();                              // weight reads done
    #pragma unroll
    for (int ct = 0; ct < 8; ++ct) {
        int col = ct * 16 + l15;
        float bv = bias[col];
        #pragma unroll
        for (int rt = 0; rt < 2; ++rt)
            #pragma unroll
            for (int j = 0; j < 4; ++j) {
                int lrow = w * 32 + rt * 16 + l4 * 4 + j;
                lw[lrow * HD + ((col + ((lrow & 15) << 3)) & 127)] =
                    keyof(f2bf(acc[rt][ct][j] + bv));
            }
    }
    __syncthreads();
    int row = tid >> 1, cb = (tid & 1) * 64;
    int r = blockIdx.x * 128 + row;
    if (r < nrows) {
        int sof = (row & 15) << 3;
        #pragma unroll
        for (int gg = 0; gg < 8; ++gg) {
            uint4t v = *(const uint4t*)&lw[row * HD + ((cb + gg * 8 + sof) & 127)];
            *(uint4t*)(hkey + (size_t)(row_base + r) * HD + cb + gg * 8) = v;
        }
    }
}

// -------- segment max on u16 keys; coalesced csr + independent gathers -------
__global__ __launch_bounds__(256) void agg_key_k(
    const uint4t* __restrict__ hkey4,            // row = 16 x uint4 (256 B)
    const int* __restrict__ off, const int* __restrict__ csr,
    uint4t* __restrict__ agg4) {
    int node = (blockIdx.x * 256 + threadIdx.x) >> 6;
    int lane = threadIdx.x & 63;
    if (node >= NN) return;
    int s0 = off[node], s1 = off[node + 1];
    int deg = s1 - s0;
    int q = lane >> 4, l16 = lane & 15;
    ushort8t m = {0, 0, 0, 0, 0, 0, 0, 0};       // 0 < key(any finite bf16)
    int cval = (lane < deg) ? csr[s0 + lane] : 0;
    int nslots = deg < 64 ? deg : 64;
    int niter = (nslots + 3) >> 2;               // wave-uniform trip count
    for (int u = 0; u < niter; ++u) {
        int idx = u * 4 + q;
        int r = __shfl(cval, idx, 64);
        if (idx < nslots) {
            uint4t v = hkey4[(size_t)r * 16 + l16];
            m = pkmax8(m, *(ushort8t*)&v);
        }
    }
    for (int base = s0 + 64; base < s1; base += 32) {
        #pragma unroll
        for (int u = 0; u < 8; ++u) {
            int jj = base + u * 4 + q;
            if (jj < s1) {
                int r = csr[jj];
                uint4t v = hkey4[(size_t)r * 16 + l16];
                m = pkmax8(m, *(ushort8t*)&v);
            }
        }
    }
    uint4t mu = *(uint4t*)&m;
    #pragma unroll
    for (int c = 0; c < 4; ++c) {
        unsigned a = mu[c];
        unsigned b = (unsigned)__shfl_xor((int)a, 16, 64);
        ushort2t pa = *(ushort2t*)&a, pb = *(ushort2t*)&b;
        pa = __builtin_elementwise_max(pa, pb);
        a = *(unsigned*)&pa;
        b = (unsigned)__shfl_xor((int)a, 32, 64);
        pb = *(ushort2t*)&b;
        pa = __builtin_elementwise_max(pa, pb);
        mu[c] = *(unsigned*)&pa;
    }
    if (q == 0) {
        uint4t outv = {0, 0, 0, 0};
        if (deg > 0) {
            #pragma unroll
            for (int c = 0; c < 4; ++c) outv[c] = unkey32(mu[c]);
        }
        agg4[(size_t)node * 16 + l16] = outv;
    }
}

// ----- combine: out = bl + agg@wl.T + h@(wr+I).T (relu?) -----
// 512 threads / 8 waves / 256 rows; LDS-staged weights; two-phase fp32 epilogue.
__global__ __launch_bounds__(512) void combine_mfma_k(
    const unsigned short* __restrict__ hkey, const unsigned short* __restrict__ aggb,
    const unsigned short* __restrict__ wlb, const float* __restrict__ bl,
    const unsigned short* __restrict__ wrb,
    unsigned short* __restrict__ hkey_out, float* __restrict__ fout, int relu) {
    __shared__ unsigned short lw[2][HD * HD];    // 64 KB weights; reused as fp32 C
    int tid = threadIdx.x;
    #pragma unroll
    for (int it = 0; it < 8; ++it) {
        int flat = (it * 512 + tid) * 4;
        int row = flat >> 7, col = flat & 127;
        *(ushort4t*)&lw[0][swz(row, col)] = *(const ushort4t*)(wlb + flat);
        *(ushort4t*)&lw[1][swz(row, col)] = *(const ushort4t*)(wrb + flat);
    }
    __syncthreads();
    int lane = tid & 63, w = tid >> 6;           // 8 waves
    int l15 = lane & 15, l4 = lane >> 4;
    int m0 = blockIdx.x * 256 + w * 32;
    const uint4t* hk4 = (const uint4t*)hkey;
    f32x4 acc[2][8] = {};
    #pragma unroll
    for (int kb = 0; kb < 4; ++kb) {
        bf16x8 a1[2], a2[2];
        #pragma unroll
        for (int rt = 0; rt < 2; ++rt) {
            int r = m0 + rt * 16 + l15;
            if (r >= NN) r = NN - 1;
            size_t o = (size_t)r * HD + kb * 32 + l4 * 8;
            a1[rt] = *(const bf16x8*)(aggb + o);
            uint4t aw = hk4[(size_t)r * 16 + kb * 4 + l4];
            bf16x8 f;
            #pragma unroll
            for (int u = 0; u < 4; ++u) {
                unsigned d = unkey32(aw[u]);
                f[2 * u]     = (short)(d & 0xFFFFu);
                f[2 * u + 1] = (short)(d >> 16);
            }
            a2[rt] = f;
        }
        #pragma unroll
        for (int ct = 0; ct < 8; ++ct) {
            bf16x8 b1 = *(const bf16x8*)&lw[0][swz(ct * 16 + l15, kb * 32 + l4 * 8)];
            bf16x8 b2 = *(const bf16x8*)&lw[1][swz(ct * 16 + l15, kb * 32 + l4 * 8)];
            acc[0][ct] = __builtin_amdgcn_mfma_f32_16x16x32_bf16(a1[0], b1, acc[0][ct], 0, 0, 0);
            acc[0][ct] = __builtin_amdgcn_mfma_f32_16x16x32_bf16(a2[0], b2, acc[0][ct], 0, 0, 0);
            acc[1][ct] = __builtin_amdgcn_mfma_f32_16x16x32_bf16(a1[1], b1, acc[1][ct], 0, 0, 0);
            acc[1][ct] = __builtin_amdgcn_mfma_f32_16x16x32_bf16(a2[1], b2, acc[1][ct], 0, 0, 0);
        }
    }
    __syncthreads();                              // weight reads done
    float* cs = (float*)lw;                       // 128 rows x 128 cols fp32
    for (int p = 0; p < 2; ++p) {
        if ((w >> 2) == p) {
            #pragma unroll
            for (int ct = 0; ct < 8; ++ct)
                #pragma unroll
                for (int rt = 0; rt < 2; ++rt)
                    #pragma unroll
                    for (int j = 0; j < 4; ++j) {
                        int lrow = (w & 3) * 32 + rt * 16 + l4 * 4 + j;
                        int col = ct * 16 + l15;
                        cs[lrow * HD + ((col + lrow * 4) & 127)] = acc[rt][ct][j];
                    }
        }
        __syncthreads();
        int lrow = tid >> 2, cq = (tid & 3) * 32;
        int r = blockIdx.x * 256 + p * 128 + lrow;
        if (r < NN) {
            const float* crow = cs + lrow * HD;
            int rot = lrow * 4;
            #pragma unroll
            for (int gg = 0; gg < 4; ++gg) {
                int c0 = cq + gg * 8;
                f32x4 cv0 = *(const f32x4*)&crow[(c0 + rot) & 127];
                f32x4 cv1 = *(const f32x4*)&crow[(c0 + 4 + rot) & 127];
                f32x4 bv0 = *(const f32x4*)(bl + c0);
                f32x4 bv1 = *(const f32x4*)(bl + c0 + 4);
                float v[8];
                #pragma unroll
                for (int u = 0; u < 4; ++u) { v[u] = cv0[u] + bv0[u]; v[u + 4] = cv1[u] + bv1[u]; }
                if (relu) {
                    #pragma unroll
                    for (int u = 0; u < 8; ++u) v[u] = fmaxf(v[u], 0.0f);
                }
                if (fout) {
                    f32x4 o0 = {v[0], v[1], v[2], v[3]};
                    f32x4 o1 = {v[4], v[5], v[6], v[7]};
                    *(f32x4*)(fout + (size_t)r * HD + c0) = o0;
                    *(f32x4*)(fout + (size_t)r * HD + c0 + 4) = o1;
                } else {
                    uint4t ov;
                    #pragma unroll
                    for (int u = 0; u < 4; ++u)
                        ov[u] = (unsigned)keyof(f2bf(v[2 * u]))
                              | ((unsigned)keyof(f2bf(v[2 * u + 1])) << 16);
                    *(uint4t*)(hkey_out + (size_t)r * HD + c0) = ov;
                }
            }
        }
        __syncthreads();
    }
}

extern "C" void kernel_launch(void* const* d_in, const int* in_sizes, int n_in,
                              void* d_out, int out_size, void* d_ws, size_t ws_size,
                              hipStream_t stream) {
    const float* x      = (const float*)d_in[0];
    const int*   ei     = (const int*)d_in[1];
    const float* w_user = (const float*)d_in[3];
    const float* b_user = (const float*)d_in[4];
    const float* w_item = (const float*)d_in[5];
    const float* b_item = (const float*)d_in[6];
    const float* w_l0   = (const float*)d_in[7];
    const float* b_l0   = (const float*)d_in[8];
    const float* w_r0   = (const float*)d_in[9];
    const float* w_l1   = (const float*)d_in[10];
    const float* b_l1   = (const float*)d_in[11];
    const float* w_r1   = (const float*)d_in[12];

    const int* e_src = ei;
    const int* e_dst = ei + EE;

    char* ws = (char*)d_ws;
    size_t cur_off = 0;
    auto carve = [&](size_t bytes) {
        void* p = ws + cur_off;
        cur_off = (cur_off + bytes + 255) & ~(size_t)255;
        return p;
    };
    unsigned short* hkey0 = (unsigned short*)carve((size_t)NN * HD * 2);  // 25.6 MB
    unsigned short* hkey1 = (unsigned short*)carve((size_t)NN * HD * 2);
    unsigned short* aggb  = (unsigned short*)carve((size_t)NN * HD * 2);
    unsigned short* wb    = (unsigned short*)carve((size_t)6 * HD * HD * 2);
    int*      off   = (int*)carve((size_t)(NN + 1) * 4);
    int*      csr   = (int*)carve((size_t)EE * 4);
    unsigned* bedge = (unsigned*)carve((size_t)EE * 4);
    int*      bcnt  = (int*)carve((NB + 1) * 4);
    int*      bbase = (int*)carve((NB + 1) * 4);
    int*      bcur  = (int*)carve((NB + 1) * 4);
    (void)ws_size;

    // ---- CSR build (bucket binning) ----
    hipMemsetAsync(bcnt, 0, (size_t)NB * 4, stream);
    int nbB = (EE + EPB - 1) / EPB;
    bhist_k<<<nbB, 256, 0, stream>>>(e_dst, bcnt);
    bscan_k<<<1, 256, 0, stream>>>(bcnt, bbase, bcur, off);
    bscatter_k<<<nbB, 256, 0, stream>>>(e_src, e_dst, bcur, bedge);
    bcsr_k<<<NB, 512, 0, stream>>>(bedge, bbase, off, csr);

    // ---- weights -> bf16 row-major (wr0/wr1 get +I) ----
    cvt6i_k<<<(6 * HD * HD) / 256, 256, 0, stream>>>(w_user, w_item, w_l0, w_r0, w_l1, w_r1, wb);

    // ---- input projection (per node type), keys only ----
    proj_mfma_k<<<(NUSR + 127) / 128, 256, 0, stream>>>(x, wb,         b_user, hkey0, 0,    NUSR);
    proj_mfma_k<<<(NITM + 127) / 128, 256, 0, stream>>>(x, wb + 16384, b_item, hkey0, NUSR, NITM);

    // ---- layer 0 ----
    agg_key_k<<<NN / 4, 256, 0, stream>>>((const uint4t*)hkey0, off, csr, (uint4t*)aggb);
    combine_mfma_k<<<(NN + 255) / 256, 512, 0, stream>>>(
        hkey0, aggb, wb + 2 * 16384, b_l0, wb + 3 * 16384, hkey1, nullptr, 1);

    // ---- layer 1 ----
    agg_key_k<<<NN / 4, 256, 0, stream>>>((const uint4t*)hkey1, off, csr, (uint4t*)aggb);
    combine_mfma_k<<<(NN + 255) / 256, 512, 0, stream>>>(
        hkey1, aggb, wb + 4 * 16384, b_l1, wb + 5 * 16384, nullptr, (float*)d_out, 0);
}

// Round 12
// 290.125 us; speedup vs baseline: 2.6323x; 1.0526x over previous
//
#include <hip/hip_runtime.h>

#define NUSR 60000
#define NITM 40000
#define NN   100000
#define EE   2000000
#define HD   128

#define BW   512                 // bucket width in nodes (CSR build)
#define NB   196                 // ceil(NN / BW)
#define EPB  8192                // edges per block in binning kernels
#define NBLK 245                 // ceil(EE / EPB)

using bf16x8   = __attribute__((ext_vector_type(8))) short;
using f32x4    = __attribute__((ext_vector_type(4))) float;
using ushort4t = __attribute__((ext_vector_type(4))) unsigned short;
using ushort2t = __attribute__((ext_vector_type(2))) unsigned short;
using ushort8t = __attribute__((ext_vector_type(8))) unsigned short;
using uint4t   = __attribute__((ext_vector_type(4))) unsigned int;

__device__ __forceinline__ unsigned short f2bf(float f) {
    unsigned int u = __float_as_uint(f);
    u += 0x7FFFu + ((u >> 16) & 1u);           // round-to-nearest-even
    return (unsigned short)(u >> 16);
}
__device__ __forceinline__ float bf2f(unsigned short s) {
    return __uint_as_float(((unsigned int)s) << 16);
}
// order-preserving bf16 <-> u16 key (unsigned compare order == float order)
__device__ __forceinline__ unsigned short keyof(unsigned short b) {
    return (b & 0x8000u) ? (unsigned short)~b : (unsigned short)(b | 0x8000u);
}
// packed inverse key map on a u32 (2 keys)
__device__ __forceinline__ unsigned unkey32(unsigned k) {
    unsigned negsel = (~k & 0x80008000u) >> 15;
    return k ^ (0x80008000u | (negsel * 0x7FFFu));
}
__device__ __forceinline__ int swz(int row, int col) {
    return row * HD + (col ^ ((row & 7) << 3));
}
__device__ __forceinline__ ushort8t pkmax8(ushort8t a, ushort8t b) {
    return __builtin_elementwise_max(a, b);
}

// ---------------- CSR build via 2-level bucket binning ----------------
// pass 1: per-block histograms -> gh[block][bin], totals -> bcnt
__global__ __launch_bounds__(256) void bhist_k(const int* __restrict__ dst,
                                               int* __restrict__ gh,
                                               int* __restrict__ bcnt) {
    __shared__ int h[NB];
    int t = threadIdx.x;
    if (t < NB) h[t] = 0;
    __syncthreads();
    int e0 = blockIdx.x * EPB;
    #pragma unroll 4
    for (int i = t; i < EPB; i += 256) {
        int e = e0 + i;
        if (e < EE) atomicAdd(&h[dst[e] >> 9], 1);
    }
    __syncthreads();
    if (t < NB) {
        gh[blockIdx.x * NB + t] = h[t];
        if (h[t]) atomicAdd(&bcnt[t], h[t]);
    }
}

// global bin scan: bcnt -> bbase (exclusive), bbase[NB] = EE, off[NN] = EE
__global__ void bscan_k(const int* __restrict__ bcnt, int* __restrict__ bbase,
                        int* __restrict__ off) {
    __shared__ int s[256];
    int t = threadIdx.x;
    int v = (t < NB) ? bcnt[t] : 0;
    s[t] = v;
    __syncthreads();
    for (int d = 1; d < 256; d <<= 1) {
        int a = (t >= d) ? s[t - d] : 0;
        __syncthreads();
        s[t] += a;
        __syncthreads();
    }
    if (t < NB) bbase[t] = s[t] - v;
    if (t == NB - 1) { bbase[NB] = s[t]; off[NN] = EE; }
}

// per-bin prefix over blocks: gh[b][bin] <- bbase[bin] + sum_{b'<b} gh[b'][bin]
__global__ void bprefix_k(int* __restrict__ gh, const int* __restrict__ bbase) {
    __shared__ int s[256];
    int bin = blockIdx.x, t = threadIdx.x;
    int v = (t < NBLK) ? gh[t * NB + bin] : 0;
    s[t] = v;
    __syncthreads();
    for (int d = 1; d < 256; d <<= 1) {
        int a = (t >= d) ? s[t - d] : 0;
        __syncthreads();
        s[t] += a;
        __syncthreads();
    }
    if (t < NBLK) gh[t * NB + bin] = bbase[bin] + s[t] - v;
}

// single-pass scatter using precomputed per-(block,bin) bases
__global__ __launch_bounds__(256) void bscatter_k(const int* __restrict__ src,
                                                  const int* __restrict__ dst,
                                                  const int* __restrict__ gh,
                                                  unsigned int* __restrict__ bedge) {
    __shared__ int h[NB], base[NB];
    int t = threadIdx.x;
    if (t < NB) { base[t] = gh[blockIdx.x * NB + t]; h[t] = 0; }
    __syncthreads();
    int e0 = blockIdx.x * EPB;
    #pragma unroll 4
    for (int i = t; i < EPB; i += 256) {
        int e = e0 + i;
        if (e < EE) {
            int d = dst[e];
            int b = d >> 9;
            int p = base[b] + atomicAdd(&h[b], 1);
            bedge[p] = ((unsigned)(d - (b << 9)) << 17) | (unsigned)src[e];
        }
    }
}

__global__ __launch_bounds__(512) void bcsr_k(const unsigned int* __restrict__ bedge,
                                              const int* __restrict__ bbase,
                                              int* __restrict__ off,
                                              int* __restrict__ csr) {
    __shared__ int cnt[BW], cur[BW], sc[BW];
    int b = blockIdx.x, t = threadIdx.x;
    int n0 = b * BW;
    int nloc = min(BW, NN - n0);
    cnt[t] = 0;
    __syncthreads();
    int e0 = bbase[b], e1 = bbase[b + 1];
    for (int e = e0 + t; e < e1; e += 512)
        atomicAdd(&cnt[bedge[e] >> 17], 1);
    __syncthreads();
    int v = cnt[t];
    sc[t] = v;
    __syncthreads();
    for (int d = 1; d < BW; d <<= 1) {
        int a = (t >= d) ? sc[t - d] : 0;
        __syncthreads();
        sc[t] += a;
        __syncthreads();
    }
    int excl = sc[t] - v;
    if (t < nloc) { off[n0 + t] = e0 + excl; cur[t] = e0 + excl; }
    __syncthreads();
    for (int e = e0 + t; e < e1; e += 512) {
        unsigned ed = bedge[e];
        int p = atomicAdd(&cur[ed >> 17], 1);
        csr[p] = (int)(ed & 0x1FFFFu);
    }
}

// ---- fp32 -> bf16 row-major weights; wr0/wr1 (m=3,5) get +I (residual fold) --
__global__ void cvt6i_k(const float* __restrict__ a0, const float* __restrict__ a1,
                        const float* __restrict__ a2, const float* __restrict__ a3,
                        const float* __restrict__ a4, const float* __restrict__ a5,
                        unsigned short* __restrict__ out) {
    int i = blockIdx.x * 256 + threadIdx.x;
    int m = i >> 14, idx = i & 16383;
    const float* s;
    switch (m) {
        case 0: s = a0; break; case 1: s = a1; break; case 2: s = a2; break;
        case 3: s = a3; break; case 4: s = a4; break; default: s = a5; break;
    }
    float v = s[idx];
    if ((m == 3 || m == 5) && (idx >> 7) == (idx & 127)) v += 1.0f;
    out[i] = f2bf(v);
}

// -------- proj: hkey[row] = key(bf16( x[row] @ w.T + b )), MFMA --------
__global__ __launch_bounds__(256) void proj_mfma_k(
    const float* __restrict__ x, const unsigned short* __restrict__ wb,
    const float* __restrict__ bias, unsigned short* __restrict__ hkey,
    int row_base, int nrows) {
    __shared__ unsigned short lw[HD * HD];       // weights, then reused as key stage
    int tid = threadIdx.x;
    #pragma unroll
    for (int it = 0; it < 16; ++it) {
        int flat = (it * 256 + tid) * 4;
        int row = flat >> 7, col = flat & 127;
        *(ushort4t*)&lw[swz(row, col)] = *(const ushort4t*)(wb + flat);
    }
    __syncthreads();
    int lane = tid & 63, w = tid >> 6;
    int l15 = lane & 15, l4 = lane >> 4;
    int m0 = blockIdx.x * 128 + w * 32;
    f32x4 acc[2][8] = {};
    #pragma unroll
    for (int kb = 0; kb < 4; ++kb) {
        bf16x8 a[2];
        #pragma unroll
        for (int rt = 0; rt < 2; ++rt) {
            int r = m0 + rt * 16 + l15;
            if (r >= nrows) r = nrows - 1;
            const float* ap = x + (size_t)(row_base + r) * HD + kb * 32 + l4 * 8;
            f32x4 v0 = *(const f32x4*)ap;
            f32x4 v1 = *(const f32x4*)(ap + 4);
            bf16x8 f;
            #pragma unroll
            for (int j = 0; j < 4; ++j) { f[j] = (short)f2bf(v0[j]); f[j + 4] = (short)f2bf(v1[j]); }
            a[rt] = f;
        }
        #pragma unroll
        for (int ct = 0; ct < 8; ++ct) {
            bf16x8 b = *(const bf16x8*)&lw[swz(ct * 16 + l15, kb * 32 + l4 * 8)];
            acc[0][ct] = __builtin_amdgcn_mfma_f32_16x16x32_bf16(a[0], b, acc[0][ct], 0, 0, 0);
            acc[1][ct] = __builtin_amdgcn_mfma_f32_16x16x32_bf16(a[1], b, acc[1][ct], 0, 0, 0);
        }
    }
    __syncthreads();                              // weight reads done
    #pragma unroll
    for (int ct = 0; ct < 8; ++ct) {
        int col = ct * 16 + l15;
        float bv = bias[col];
        #pragma unroll
        for (int rt = 0; rt < 2; ++rt)
            #pragma unroll
            for (int j = 0; j < 4; ++j) {
                int lrow = w * 32 + rt * 16 + l4 * 4 + j;
                lw[lrow * HD + ((col + ((lrow & 15) << 3)) & 127)] =
                    keyof(f2bf(acc[rt][ct][j] + bv));
            }
    }
    __syncthreads();
    int row = tid >> 1, cb = (tid & 1) * 64;
    int r = blockIdx.x * 128 + row;
    if (r < nrows) {
        int sof = (row & 15) << 3;
        #pragma unroll
        for (int gg = 0; gg < 8; ++gg) {
            uint4t v = *(const uint4t*)&lw[row * HD + ((cb + gg * 8 + sof) & 127)];
            *(uint4t*)(hkey + (size_t)(row_base + r) * HD + cb + gg * 8) = v;
        }
    }
}

// -------- segment max on u16 keys; coalesced csr + independent gathers -------
__global__ __launch_bounds__(256) void agg_key_k(
    const uint4t* __restrict__ hkey4,            // row = 16 x uint4 (256 B)
    const int* __restrict__ off, const int* __restrict__ csr,
    uint4t* __restrict__ agg4) {
    int node = (blockIdx.x * 256 + threadIdx.x) >> 6;
    int lane = threadIdx.x & 63;
    if (node >= NN) return;
    int s0 = off[node], s1 = off[node + 1];
    int deg = s1 - s0;
    int q = lane >> 4, l16 = lane & 15;
    ushort8t m = {0, 0, 0, 0, 0, 0, 0, 0};       // 0 < key(any finite bf16)
    int cval = (lane < deg) ? csr[s0 + lane] : 0;
    int nslots = deg < 64 ? deg : 64;
    int niter = (nslots + 3) >> 2;               // wave-uniform trip count
    for (int u = 0; u < niter; ++u) {
        int idx = u * 4 + q;
        int r = __shfl(cval, idx, 64);
        if (idx < nslots) {
            uint4t v = hkey4[(size_t)r * 16 + l16];
            m = pkmax8(m, *(ushort8t*)&v);
        }
    }
    for (int base = s0 + 64; base < s1; base += 32) {
        #pragma unroll
        for (int u = 0; u < 8; ++u) {
            int jj = base + u * 4 + q;
            if (jj < s1) {
                int r = csr[jj];
                uint4t v = hkey4[(size_t)r * 16 + l16];
                m = pkmax8(m, *(ushort8t*)&v);
            }
        }
    }
    uint4t mu = *(uint4t*)&m;
    #pragma unroll
    for (int c = 0; c < 4; ++c) {
        unsigned a = mu[c];
        unsigned b = (unsigned)__shfl_xor((int)a, 16, 64);
        ushort2t pa = *(ushort2t*)&a, pb = *(ushort2t*)&b;
        pa = __builtin_elementwise_max(pa, pb);
        a = *(unsigned*)&pa;
        b = (unsigned)__shfl_xor((int)a, 32, 64);
        pb = *(ushort2t*)&b;
        pa = __builtin_elementwise_max(pa, pb);
        mu[c] = *(unsigned*)&pa;
    }
    if (q == 0) {
        uint4t outv = {0, 0, 0, 0};
        if (deg > 0) {
            #pragma unroll
            for (int c = 0; c < 4; ++c) outv[c] = unkey32(mu[c]);
        }
        agg4[(size_t)node * 16 + l16] = outv;
    }
}

// ----- combine: out = bl + agg@wl.T + h@(wr+I).T (relu?) -----
// 512 threads / 8 waves / 256 rows; LDS-staged weights.
// fp32 output: direct C-fragment stores (4x64B/wave-store). bf16 keys: LDS bounce.
__global__ __launch_bounds__(512) void combine_mfma_k(
    const unsigned short* __restrict__ hkey, const unsigned short* __restrict__ aggb,
    const unsigned short* __restrict__ wlb, const float* __restrict__ bl,
    const unsigned short* __restrict__ wrb,
    unsigned short* __restrict__ hkey_out, float* __restrict__ fout, int relu) {
    __shared__ unsigned short lw[2][HD * HD];    // 64 KB weights; reused as fp32 C
    int tid = threadIdx.x;
    #pragma unroll
    for (int it = 0; it < 8; ++it) {
        int flat = (it * 512 + tid) * 4;
        int row = flat >> 7, col = flat & 127;
        *(ushort4t*)&lw[0][swz(row, col)] = *(const ushort4t*)(wlb + flat);
        *(ushort4t*)&lw[1][swz(row, col)] = *(const ushort4t*)(wrb + flat);
    }
    __syncthreads();
    int lane = tid & 63, w = tid >> 6;           // 8 waves
    int l15 = lane & 15, l4 = lane >> 4;
    int m0 = blockIdx.x * 256 + w * 32;
    const uint4t* hk4 = (const uint4t*)hkey;
    f32x4 acc[2][8] = {};
    #pragma unroll
    for (int kb = 0; kb < 4; ++kb) {
        bf16x8 a1[2], a2[2];
        #pragma unroll
        for (int rt = 0; rt < 2; ++rt) {
            int r = m0 + rt * 16 + l15;
            if (r >= NN) r = NN - 1;
            size_t o = (size_t)r * HD + kb * 32 + l4 * 8;
            a1[rt] = *(const bf16x8*)(aggb + o);
            uint4t aw = hk4[(size_t)r * 16 + kb * 4 + l4];
            bf16x8 f;
            #pragma unroll
            for (int u = 0; u < 4; ++u) {
                unsigned d = unkey32(aw[u]);
                f[2 * u]     = (short)(d & 0xFFFFu);
                f[2 * u + 1] = (short)(d >> 16);
            }
            a2[rt] = f;
        }
        #pragma unroll
        for (int ct = 0; ct < 8; ++ct) {
            bf16x8 b1 = *(const bf16x8*)&lw[0][swz(ct * 16 + l15, kb * 32 + l4 * 8)];
            bf16x8 b2 = *(const bf16x8*)&lw[1][swz(ct * 16 + l15, kb * 32 + l4 * 8)];
            acc[0][ct] = __builtin_amdgcn_mfma_f32_16x16x32_bf16(a1[0], b1, acc[0][ct], 0, 0, 0);
            acc[0][ct] = __builtin_amdgcn_mfma_f32_16x16x32_bf16(a2[0], b2, acc[0][ct], 0, 0, 0);
            acc[1][ct] = __builtin_amdgcn_mfma_f32_16x16x32_bf16(a1[1], b1, acc[1][ct], 0, 0, 0);
            acc[1][ct] = __builtin_amdgcn_mfma_f32_16x16x32_bf16(a2[1], b2, acc[1][ct], 0, 0, 0);
        }
    }
    if (fout) {
        // direct C-fragment stores: lanes l15=0..15 cover 16 consecutive cols
        // -> each wave-store is 4 segments of 64 B. No barriers needed.
        #pragma unroll
        for (int ct = 0; ct < 8; ++ct) {
            int col = ct * 16 + l15;
            float bv = bl[col];
            #pragma unroll
            for (int rt = 0; rt < 2; ++rt)
                #pragma unroll
                for (int j = 0; j < 4; ++j) {
                    int r = m0 + rt * 16 + l4 * 4 + j;
                    if (r < NN) {
                        float v = acc[rt][ct][j] + bv;
                        if (relu) v = fmaxf(v, 0.0f);
                        fout[(size_t)r * HD + col] = v;
                    }
                }
        }
        return;
    }
    __syncthreads();                              // weight reads done
    float* cs = (float*)lw;                       // 128 rows x 128 cols fp32
    for (int p = 0; p < 2; ++p) {
        if ((w >> 2) == p) {
            #pragma unroll
            for (int ct = 0; ct < 8; ++ct)
                #pragma unroll
                for (int rt = 0; rt < 2; ++rt)
                    #pragma unroll
                    for (int j = 0; j < 4; ++j) {
                        int lrow = (w & 3) * 32 + rt * 16 + l4 * 4 + j;
                        int col = ct * 16 + l15;
                        cs[lrow * HD + ((col + lrow * 4) & 127)] = acc[rt][ct][j];
                    }
        }
        __syncthreads();
        int lrow = tid >> 2, cq = (tid & 3) * 32;
        int r = blockIdx.x * 256 + p * 128 + lrow;
        if (r < NN) {
            const float* crow = cs + lrow * HD;
            int rot = lrow * 4;
            #pragma unroll
            for (int gg = 0; gg < 4; ++gg) {
                int c0 = cq + gg * 8;
                f32x4 cv0 = *(const f32x4*)&crow[(c0 + rot) & 127];
                f32x4 cv1 = *(const f32x4*)&crow[(c0 + 4 + rot) & 127];
                f32x4 bv0 = *(const f32x4*)(bl + c0);
                f32x4 bv1 = *(const f32x4*)(bl + c0 + 4);
                float v[8];
                #pragma unroll
                for (int u = 0; u < 4; ++u) { v[u] = cv0[u] + bv0[u]; v[u + 4] = cv1[u] + bv1[u]; }
                if (relu) {
                    #pragma unroll
                    for (int u = 0; u < 8; ++u) v[u] = fmaxf(v[u], 0.0f);
                }
                uint4t ov;
                #pragma unroll
                for (int u = 0; u < 4; ++u)
                    ov[u] = (unsigned)keyof(f2bf(v[2 * u]))
                          | ((unsigned)keyof(f2bf(v[2 * u + 1])) << 16);
                *(uint4t*)(hkey_out + (size_t)r * HD + c0) = ov;
            }
        }
        __syncthreads();
    }
}

extern "C" void kernel_launch(void* const* d_in, const int* in_sizes, int n_in,
                              void* d_out, int out_size, void* d_ws, size_t ws_size,
                              hipStream_t stream) {
    const float* x      = (const float*)d_in[0];
    const int*   ei     = (const int*)d_in[1];
    const float* w_user = (const float*)d_in[3];
    const float* b_user = (const float*)d_in[4];
    const float* w_item = (const float*)d_in[5];
    const float* b_item = (const float*)d_in[6];
    const float* w_l0   = (const float*)d_in[7];
    const float* b_l0   = (const float*)d_in[8];
    const float* w_r0   = (const float*)d_in[9];
    const float* w_l1   = (const float*)d_in[10];
    const float* b_l1   = (const float*)d_in[11];
    const float* w_r1   = (const float*)d_in[12];

    const int* e_src = ei;
    const int* e_dst = ei + EE;

    char* ws = (char*)d_ws;
    size_t cur_off = 0;
    auto carve = [&](size_t bytes) {
        void* p = ws + cur_off;
        cur_off = (cur_off + bytes + 255) & ~(size_t)255;
        return p;
    };
    unsigned short* hkey0 = (unsigned short*)carve((size_t)NN * HD * 2);  // 25.6 MB
    unsigned short* hkey1 = (unsigned short*)carve((size_t)NN * HD * 2);
    unsigned short* aggb  = (unsigned short*)carve((size_t)NN * HD * 2);
    unsigned short* wb    = (unsigned short*)carve((size_t)6 * HD * HD * 2);
    int*      off   = (int*)carve((size_t)(NN + 1) * 4);
    int*      csr   = (int*)carve((size_t)EE * 4);
    unsigned* bedge = (unsigned*)carve((size_t)EE * 4);
    int*      gh    = (int*)carve((size_t)NBLK * NB * 4);    // 192 KB
    int*      bcnt  = (int*)carve((NB + 1) * 4);
    int*      bbase = (int*)carve((NB + 1) * 4);
    (void)ws_size;

    // ---- CSR build (bucket binning, single-pass scatter) ----
    hipMemsetAsync(bcnt, 0, (size_t)NB * 4, stream);
    bhist_k<<<NBLK, 256, 0, stream>>>(e_dst, gh, bcnt);
    bscan_k<<<1, 256, 0, stream>>>(bcnt, bbase, off);
    bprefix_k<<<NB, 256, 0, stream>>>(gh, bbase);
    bscatter_k<<<NBLK, 256, 0, stream>>>(e_src, e_dst, gh, bedge);
    bcsr_k<<<NB, 512, 0, stream>>>(bedge, bbase, off, csr);

    // ---- weights -> bf16 row-major (wr0/wr1 get +I) ----
    cvt6i_k<<<(6 * HD * HD) / 256, 256, 0, stream>>>(w_user, w_item, w_l0, w_r0, w_l1, w_r1, wb);

    // ---- input projection (per node type), keys only ----
    proj_mfma_k<<<(NUSR + 127) / 128, 256, 0, stream>>>(x, wb,         b_user, hkey0, 0,    NUSR);
    proj_mfma_k<<<(NITM + 127) / 128, 256, 0, stream>>>(x, wb + 16384, b_item, hkey0, NUSR, NITM);

    // ---- layer 0 ----
    agg_key_k<<<NN / 4, 256, 0, stream>>>((const uint4t*)hkey0, off, csr, (uint4t*)aggb);
    combine_mfma_k<<<(NN + 255) / 256, 512, 0, stream>>>(
        hkey0, aggb, wb + 2 * 16384, b_l0, wb + 3 * 16384, hkey1, nullptr, 1);

    // ---- layer 1 ----
    agg_key_k<<<NN / 4, 256, 0, stream>>>((const uint4t*)hkey1, off, csr, (uint4t*)aggb);
    combine_mfma_k<<<(NN + 255) / 256, 512, 0, stream>>>(
        hkey1, aggb, wb + 4 * 16384, b_l1, wb + 5 * 16384, nullptr, (float*)d_out, 0);
}